// Round 3
// baseline (150.291 us; speedup 1.0000x reference)
//
#include <hip/hip_runtime.h>
#include <hip/hip_bf16.h>
#include <math.h>

#define Fdim 40
#define Edim 64
#define K2   128
#define Tdim 2
#define EPSV 1e-5f

typedef __attribute__((ext_vector_type(8))) short short8;
typedef __attribute__((ext_vector_type(4))) float f32x4;

__device__ __forceinline__ short f2b(float f) {
    unsigned u = __builtin_bit_cast(unsigned, f);
    unsigned r = (u + 0x7fffu + ((u >> 16) & 1u)) >> 16;
    return (short)r;
}
__device__ __forceinline__ float b2f(short h) {
    unsigned u = ((unsigned)(unsigned short)h) << 16;
    return __builtin_bit_cast(float, u);
}
__device__ __forceinline__ f32x4 mfma16(short8 a, short8 b, f32x4 c) {
    return __builtin_amdgcn_mfma_f32_16x16x32_bf16(a, b, c, 0, 0, 0);
}
// swizzled byte offset within a [48][64] bf16 buffer (row stride 128 B)
__device__ __forceinline__ int swz(int f, int e2 /*byte col*/) {
    return (f * 128 + e2) ^ ((f & 7) << 4);
}

// ws layout:
//   adjT bf16 [2][48][64]   : shorts 0      .. 6144
//   WT   bf16 [2][64][128]  : shorts 6144   .. 22528
//   gwT  bf16 [48][2560]    : shorts 22528  .. 145408
//   bnS  f32  [2][40][128]  : floats at short-index 145408
//   bnO  f32  [2][40][128]

// ---------------------------------------------------------------------------
__global__ void adj_kernel(const float* __restrict__ masker,
                           const float* __restrict__ ln_gamma,
                           const float* __restrict__ ln_beta,
                           short* __restrict__ adjT) {
    const int t = blockIdx.x;
    const int tid = threadIdx.x;
    __shared__ float araw[Fdim][Fdim];

    for (int i = tid; i < Fdim * Fdim; i += 64) {
        int g = i / Fdim, ff = i % Fdim;
        const float* mb = masker + t * (3 * Fdim * Fdim) + g * Fdim + ff;
        float p = mb[0] * mb[Fdim * Fdim] * mb[2 * Fdim * Fdim];
        araw[g][ff] = p > 0.f ? p : 0.f;
    }
    __syncthreads();

    const int f = tid;
    if (f < 40) {
        float mu = 0.f, m2 = 0.f;
        #pragma unroll
        for (int g = 0; g < Fdim; ++g) {
            float v = araw[g][f];
            mu += v; m2 += v * v;
        }
        mu *= (1.f / Fdim); m2 *= (1.f / Fdim);
        float inv = rsqrtf(m2 - mu * mu + EPSV);

        float logits[Fdim];
        float mx = -1e30f;
        #pragma unroll
        for (int g = 0; g < Fdim; ++g) {
            float v = araw[g][f];
            float l = (v - mu) * inv * ln_gamma[g] + ln_beta[g];
            if (v == 0.f) l += -1e9f;
            if (g == f) l += 1.f;
            logits[g] = l;
            mx = fmaxf(mx, l);
        }
        float den = 0.f;
        #pragma unroll
        for (int g = 0; g < Fdim; ++g) {
            float p = expf(logits[g] - mx);
            logits[g] = p;
            den += p;
        }
        float rden = 1.f / den;
        short* row = adjT + t * 3072 + f * 64;   // adjT[t][f][g]
        #pragma unroll
        for (int g = 0; g < Fdim; ++g) {
            float msk = (araw[g][f] != 0.f) ? 1.f : 0.f;
            row[g] = f2b(logits[g] * rden * msk);
        }
        for (int g = Fdim; g < 64; ++g) row[g] = 0;
    } else if (f < 48) {
        short* row = adjT + t * 3072 + f * 64;
        for (int g = 0; g < 64; ++g) row[g] = 0;
    }
}

// ---------------------------------------------------------------------------
__global__ void prep_kernel(const float* __restrict__ w_t,
                            const float* __restrict__ gate_w,
                            const float* __restrict__ bn_gamma,
                            const float* __restrict__ bn_beta,
                            const float* __restrict__ bn_mean,
                            const float* __restrict__ bn_var,
                            short* __restrict__ WT,
                            short* __restrict__ gwT,
                            float* __restrict__ bnS,
                            float* __restrict__ bnO) {
    int i = blockIdx.x * 256 + threadIdx.x;
    if (i < 16384) {
        int t = i >> 13, r = i & 8191, e = r >> 7, k = r & 127;
        WT[i] = f2b(w_t[t * 8192 + k * 64 + e]);
    } else if (i < 139264) {
        int j = i - 16384;
        int fo = j / 2560, k = j - fo * 2560;
        gwT[j] = (fo < 40) ? f2b(gate_w[k * 40 + fo]) : (short)0;
    } else if (i < 149504) {
        int j = i - 139264;
        float s = bn_gamma[j] * rsqrtf(bn_var[j] + EPSV);
        bnS[j] = s;
        bnO[j] = bn_beta[j] - bn_mean[j] * s;
    }
}

// ---------------------------------------------------------------------------
// main: 256 thr / 4 waves; wave w owns sample (blockIdx*4 + w), BOTH towers.
// Per-wave 12288 B region: [0,6144) xT stage (later xcur_t1), [6144,12288) buf0
// (nei_t0 -> xcur_t0). Block: 8 sample-towers. 3 barriers total.
// ---------------------------------------------------------------------------
__global__ __launch_bounds__(256, 2) void main_kernel(
    const float* __restrict__ x,
    const short* __restrict__ adjT,
    const short* __restrict__ WT,
    const short* __restrict__ gwT,
    const float* __restrict__ bnS,
    const float* __restrict__ bnO,
    const float* __restrict__ b_t,
    const float* __restrict__ gate_b,
    float* __restrict__ out)
{
    extern __shared__ char smem[];
    const int tid = threadIdx.x;
    const int w = tid >> 6, lane = tid & 63;
    const int er = lane & 15, q = lane >> 4;
    const int bbase = blockIdx.x * 4;

    char* wreg = smem + w * 12288;
    short* xTs = (short*)wreg;               // [64][48] bf16, stride 96 B
    f32x4* gred = (f32x4*)(smem + 49152);    // [4][3][64]
    float* g_lds = (float*)(smem + 61440);   // [8][40]

    // zero cols 40..47 of all 64 xT rows (one b128 per lane)
    {
        f32x4 z = {0.f, 0.f, 0.f, 0.f};
        *(f32x4*)(wreg + lane * 96 + 80) = z;
    }

    const float* xb = x + (size_t)(bbase + w) * 2560;

    // ---- stage x transposed: xT[e][g] = x[g][e]
    #pragma unroll
    for (int it = 0; it < 10; ++it) {
        int g = it * 4 + q;
        int e0 = er * 4;
        float4 xv = *(const float4*)(xb + g * 64 + e0);
        xTs[(e0 + 0) * 48 + g] = f2b(xv.x);
        xTs[(e0 + 1) * 48 + g] = f2b(xv.y);
        xTs[(e0 + 2) * 48 + g] = f2b(xv.z);
        xTs[(e0 + 3) * 48 + g] = f2b(xv.w);
    }

    // ---- build B-fragments of x (shared by both towers)
    short8 Bf[2][4];
    #pragma unroll
    for (int nt = 0; nt < 4; ++nt) {
        int e = nt * 16 + er;
        Bf[0][nt] = *(const short8*)(xTs + e * 48 + q * 8);
        // kt=1: g = 32 + q*8: q=0 real rows 32..39, q=1 hits zeroed cols 40..47,
        // q>=2 out of range -> clamp addr and zero via select
        short8 v = *(const short8*)(xTs + e * 48 + 32 + (q & 1) * 8);
        if (q >= 2) { short8 zz = {0,0,0,0,0,0,0,0}; v = zz; }
        Bf[1][nt] = v;
    }

    #pragma unroll
    for (int t = 0; t < 2; ++t) {
        short* nbuf = (short*)(t == 0 ? (wreg + 6144) : wreg); // [48][64] swz
        const short* adjTt = adjT + t * 3072;
        const short* WTt   = WT + t * 8192;
        const float* bnSt  = bnS + t * 5120;
        const float* bnOt  = bnO + t * 5120;
        const float* btt   = b_t + t * 2560;

        // ---------------- phase N: nei = adjT * x, BN2 fused on store
        #pragma unroll
        for (int mt = 0; mt < 3; ++mt) {
            const short* arow = adjTt + (mt * 16 + er) * 64 + q * 8;
            short8 A0 = *(const short8*)(arow);
            short8 A1 = *(const short8*)(arow + 32);
            #pragma unroll
            for (int nt = 0; nt < 4; ++nt) {
                f32x4 z = {0.f, 0.f, 0.f, 0.f};
                z = mfma16(A0, Bf[0][nt], z);
                f32x4 acc = mfma16(A1, Bf[1][nt], z);
                #pragma unroll
                for (int r = 0; r < 4; ++r) {
                    int f = mt * 16 + q * 4 + r;
                    if (f < 40) {
                        int e = nt * 16 + er;
                        int ci = f * 128 + 64 + e;
                        float vv = acc[r] * bnSt[ci] + bnOt[ci];
                        *(short*)((char*)nbuf + swz(f, e * 2)) = f2b(vv);
                    }
                }
            }
        }

        // ---------------- phase M: xcur = BN(concat(x,nei)) @ W + b (in place)
        #pragma unroll
        for (int mt = 0; mt < 3; ++mt) {
            f32x4 acc[4];
            #pragma unroll
            for (int nt = 0; nt < 4; ++nt) { f32x4 z = {0.f,0.f,0.f,0.f}; acc[nt] = z; }
            #pragma unroll
            for (int kt = 0; kt < 4; ++kt) {
                short8 A;
                if (kt < 2) {
                    int f = mt * 16 + er;
                    if (f < 40) {
                        int kb = kt * 32 + q * 8;
                        const float4* xp = (const float4*)(xb + f * 64 + kb);
                        float4 x0 = xp[0], x1 = xp[1];
                        const float4* sp = (const float4*)(bnSt + f * 128 + kb);
                        const float4* op = (const float4*)(bnOt + f * 128 + kb);
                        float4 s0 = sp[0], s1 = sp[1], o0 = op[0], o1 = op[1];
                        A[0] = f2b(x0.x * s0.x + o0.x);
                        A[1] = f2b(x0.y * s0.y + o0.y);
                        A[2] = f2b(x0.z * s0.z + o0.z);
                        A[3] = f2b(x0.w * s0.w + o0.w);
                        A[4] = f2b(x1.x * s1.x + o1.x);
                        A[5] = f2b(x1.y * s1.y + o1.y);
                        A[6] = f2b(x1.z * s1.z + o1.z);
                        A[7] = f2b(x1.w * s1.w + o1.w);
                    } else {
                        short8 za = {0,0,0,0,0,0,0,0};
                        A = za;
                    }
                } else {
                    int f = mt * 16 + er;
                    A = *(const short8*)((char*)nbuf + swz(f, (kt - 2) * 64 + q * 16));
                }
                #pragma unroll
                for (int nt = 0; nt < 4; ++nt) {
                    short8 B = *(const short8*)(WTt + (nt * 16 + er) * 128 + kt * 32 + q * 8);
                    acc[nt] = mfma16(A, B, acc[nt]);
                }
            }
            #pragma unroll
            for (int nt = 0; nt < 4; ++nt) {
                #pragma unroll
                for (int r = 0; r < 4; ++r) {
                    int f = mt * 16 + q * 4 + r;
                    if (f < 40) {
                        int e = nt * 16 + er;
                        float vv = acc[nt][r] + btt[f * 64 + e];
                        *(short*)((char*)nbuf + swz(f, e * 2)) = f2b(vv);
                    }
                }
            }
        }
    }

    __syncthreads();

    // ---------------- gate: M=16 (8 st used), K=2560 split 4 ways over waves
    {
        f32x4 g0 = {0.f,0.f,0.f,0.f}, g1 = g0, g2 = g0;
        int st_r = er & 7;
        const char* abase = smem + (st_r >> 1) * 12288 + ((st_r & 1) ? 0 : 6144);
        for (int kk = 0; kk < 20; ++kk) {
            int k0 = (w * 20 + kk) * 32 + q * 8;
            int f = k0 >> 6, e0 = k0 & 63;
            short8 A = *(const short8*)(abase + swz(f, e0 * 2));
            const short* gwp = gwT + k0;
            g0 = mfma16(A, *(const short8*)(gwp + er * 2560), g0);
            g1 = mfma16(A, *(const short8*)(gwp + (16 + er) * 2560), g1);
            g2 = mfma16(A, *(const short8*)(gwp + (32 + er) * 2560), g2);
        }
        gred[(w * 3 + 0) * 64 + lane] = g0;
        gred[(w * 3 + 1) * 64 + lane] = g1;
        gred[(w * 3 + 2) * 64 + lane] = g2;
    }
    __syncthreads();

    if (w < 3) {
        f32x4 v = gred[(0 * 3 + w) * 64 + lane] + gred[(1 * 3 + w) * 64 + lane]
                + gred[(2 * 3 + w) * 64 + lane] + gred[(3 * 3 + w) * 64 + lane];
        int fo = w * 16 + er;
        if (q < 2 && fo < 40) {
            float gb = gate_b[fo];
            #pragma unroll
            for (int r = 0; r < 4; ++r)
                g_lds[(q * 4 + r) * 40 + fo] = v[r] + gb;
        }
    }
    __syncthreads();

    // ---------------- final: softmax over f + weighted sum; thread -> (st, e)
    {
        int e = tid & 63;
        int st0 = tid >> 6;
        #pragma unroll
        for (int rep = 0; rep < 2; ++rep) {
            int st = st0 + rep * 4;
            const float* gr = g_lds + st * 40;
            const char* buf = smem + (st >> 1) * 12288 + ((st & 1) ? 0 : 6144);
            float m = gr[0];
            #pragma unroll
            for (int f2 = 1; f2 < 40; ++f2) m = fmaxf(m, gr[f2]);
            float den = 0.f, o = 0.f;
            #pragma unroll
            for (int f2 = 0; f2 < 40; ++f2) {
                float p = __expf(gr[f2] - m);
                den += p;
                short xv = *(const short*)(buf + swz(f2, e * 2));
                o += p * b2f(xv);
            }
            out[(size_t)(bbase * 2 + st) * 64 + e] = o / den;
        }
    }
}

extern "C" void kernel_launch(void* const* d_in, const int* in_sizes, int n_in,
                              void* d_out, int out_size, void* d_ws, size_t ws_size,
                              hipStream_t stream) {
    (void)in_sizes; (void)n_in; (void)out_size; (void)ws_size;
    const float* x        = (const float*)d_in[0];
    const float* masker   = (const float*)d_in[1];
    const float* ln_gamma = (const float*)d_in[2];
    const float* ln_beta  = (const float*)d_in[3];
    const float* w_t      = (const float*)d_in[4];
    const float* b_t      = (const float*)d_in[5];
    const float* bn_gamma = (const float*)d_in[6];
    const float* bn_beta  = (const float*)d_in[7];
    const float* bn_mean  = (const float*)d_in[8];
    const float* bn_var   = (const float*)d_in[9];
    const float* gate_w   = (const float*)d_in[10];
    const float* gate_b   = (const float*)d_in[11];
    float* out = (float*)d_out;

    short* adjT = (short*)d_ws;
    short* WT   = adjT + 6144;
    short* gwT  = WT + 16384;
    float* bnS  = (float*)(gwT + 122880);
    float* bnO  = bnS + 10240;

    adj_kernel<<<Tdim, 64, 0, stream>>>(masker, ln_gamma, ln_beta, adjT);
    prep_kernel<<<584, 256, 0, stream>>>(w_t, gate_w, bn_gamma, bn_beta, bn_mean,
                                         bn_var, WT, gwT, bnS, bnO);

    constexpr int SMEM_BYTES = 4 * 12288 + 12288 + 1280;  // 62720
    (void)hipFuncSetAttribute((const void*)main_kernel,
                              hipFuncAttributeMaxDynamicSharedMemorySize, SMEM_BYTES);
    main_kernel<<<1024, 256, SMEM_BYTES, stream>>>(
        x, adjT, WT, gwT, bnS, bnO, b_t, gate_b, out);
}